// Round 5
// baseline (101.498 us; speedup 1.0000x reference)
//
#include <hip/hip_runtime.h>

#define N_ROWS 8192
#define D_DIM  256
#define EPS    1e-6f
#define MARGIN 0.5f
#define NTILE  1056   // sum_{R=0}^{31} (64 - 2R) upper-tri 256x128 tiles

typedef __bf16 bf16x8 __attribute__((ext_vector_type(8)));
typedef float  f32x4  __attribute__((ext_vector_type(4)));

// round-to-nearest-even fp32 -> bf16
__device__ inline unsigned short f2bf(float f) {
    unsigned u = __float_as_uint(f);
    return (unsigned short)((u + 0x7FFFu + ((u >> 16) & 1u)) >> 16);
}

// async global->LDS, 16B/lane; LDS dst = wave-uniform base + lane*16 (m104/m108)
__device__ inline void gl_lds16(const void* g, void* l) {
    __builtin_amdgcn_global_load_lds(
        (const __attribute__((address_space(1))) unsigned int*)g,
        (__attribute__((address_space(3))) unsigned int*)l, 16, 0, 0);
}

// Prep v2: fp32 X -> bf16 swizzled Xs + row sums. Chunk (rb,kb) = 1KB holds
// rows [rb*16,+16) x k [kb*32,+32): elem (row,k) at lane=((k>>3)&3)*16+(row&15),
// j=k&7. One wave writes one whole chunk: STORE = base + lane*16, perfectly
// coalesced (R4 prep scattered 16B stores were ~10us). Reads are 32B/lane
// gathers, absorbed by L2/L3.
__global__ __launch_bounds__(256)
void prep_kernel(const float* __restrict__ X,
                 unsigned short* __restrict__ Xs,
                 float* __restrict__ sq, float* __restrict__ s) {
    __shared__ float lsq[64], ls[64];
    int t = threadIdx.x;
    int w = t >> 6, l = t & 63;
    int rb = blockIdx.x;
    int row = rb * 16 + (l & 15);
    int q   = l >> 4;                      // k-quarter 0..3
    float psq = 0.f, ps = 0.f;
    for (int h = 0; h < 2; h++) {
        int kb = 2 * w + h;
        int k0 = kb * 32 + q * 8;
        const float* xp = X + (size_t)row * D_DIM + k0;
        float4 v0 = ((const float4*)xp)[0];
        float4 v1 = ((const float4*)xp)[1];
        float xv[8] = {v0.x, v0.y, v0.z, v0.w, v1.x, v1.y, v1.z, v1.w};
        for (int i = 0; i < 8; i++) { psq += xv[i] * xv[i]; ps += xv[i]; }
        unsigned w0 = (unsigned)f2bf(xv[0]) | ((unsigned)f2bf(xv[1]) << 16);
        unsigned w1 = (unsigned)f2bf(xv[2]) | ((unsigned)f2bf(xv[3]) << 16);
        unsigned w2 = (unsigned)f2bf(xv[4]) | ((unsigned)f2bf(xv[5]) << 16);
        unsigned w3 = (unsigned)f2bf(xv[6]) | ((unsigned)f2bf(xv[7]) << 16);
        *(uint4*)(Xs + (size_t)(rb * 8 + kb) * 512 + (size_t)l * 8) =
            make_uint4(w0, w1, w2, w3);
    }
    // reduce k-quarters: lanes with same (l&15) share a row
    psq += __shfl_xor(psq, 16, 64); psq += __shfl_xor(psq, 32, 64);
    ps  += __shfl_xor(ps,  16, 64); ps  += __shfl_xor(ps,  32, 64);
    if (l < 16) { lsq[w * 16 + l] = psq; ls[w * 16 + l] = ps; }
    __syncthreads();
    if (t < 16) {
        float aq = 0.f, as = 0.f;
        for (int i = 0; i < 4; i++) { aq += lsq[i * 16 + t]; as += ls[i * 16 + t]; }
        sq[rb * 16 + t] = aq; s[rb * 16 + t] = as;
    }
}

// Fused gram + loss: 256x128 block tile, 512 threads = 8 waves (4x2 of 64x64
// wave tiles), double-buffered LDS (A 16KB + B 8KB per buffer) via
// global_load_lds. Triangular tile list over (R=256-row blk, c=128-col blk),
// per-64-row-strip weight {0,1,2} resolves the 128-granular diagonal.
__global__ __launch_bounds__(512)
void gram_loss_kernel(const unsigned short* __restrict__ Xs,
                      const float* __restrict__ sq, const float* __restrict__ s,
                      const int* __restrict__ tgt,
                      float* __restrict__ partials) {
    __shared__ __align__(16) unsigned short lds[2][12288]; // [buf][A:0..8191 B:8192..12287]
    __shared__ float wsum[8];

    // p -> (R, c): f(R) = R*(65-R) tiles before row-block R; c in [2R, 64)
    int p = blockIdx.x;
    int R = (int)((65.0f - sqrtf(4225.0f - 4.0f * (float)p)) * 0.5f);
    if (R < 0) R = 0; if (R > 31) R = 31;
    while (R < 31 && (R + 1) * (65 - (R + 1)) <= p) R++;
    while (R > 0 && R * (65 - R) > p) R--;
    int c = 2 * R + (p - R * (65 - R));

    int wave = threadIdx.x >> 6;
    int lane = threadIdx.x & 63;
    int wr = wave >> 1, wc = wave & 1;     // 4x2 wave grid

    // staging: 24 1KB-chunks per kb-slice (A:16, B:8); wave stages 3
    const char* xb = (const char*)Xs;
    const char* srcs[3];
    unsigned short* dsts[3];
    for (int i = 0; i < 3; i++) {
        int q = 3 * wave + i;
        int chunk = (q < 16) ? (R * 16 + q) * 8 : (c * 8 + (q - 16)) * 8;
        srcs[i] = xb + (size_t)chunk * 1024 + (size_t)lane * 16;
        dsts[i] = &lds[0][(q < 16) ? q * 512 : 8192 + (q - 16) * 512];
    }

    f32x4 acc[4][4];
    for (int r = 0; r < 4; r++)
        for (int cc = 0; cc < 4; cc++)
            for (int e = 0; e < 4; e++) acc[r][cc][e] = 0.0f;

    for (int i = 0; i < 3; i++) gl_lds16(srcs[i], dsts[i]);
    __syncthreads();

    const unsigned short* fA = &lds[0][(wr * 4) * 512] + lane * 8;
    const unsigned short* fB = &lds[0][8192 + (wc * 4) * 512] + lane * 8;

    for (int kb = 0; kb < 8; kb++) {
        int cur = kb & 1, nxt = cur ^ 1;
        if (kb < 7) {
            size_t ko = (size_t)(kb + 1) * 1024;
            for (int i = 0; i < 3; i++)
                gl_lds16(srcs[i] + ko, dsts[i] + nxt * 12288);
        }
        const unsigned short* a_p = fA + (size_t)cur * 12288;
        const unsigned short* b_p = fB + (size_t)cur * 12288;
        bf16x8 a[4], b[4];
        for (int r = 0; r < 4; r++)  a[r]  = *(const bf16x8*)(a_p + r * 512);
        for (int cc = 0; cc < 4; cc++) b[cc] = *(const bf16x8*)(b_p + cc * 512);
        for (int r = 0; r < 4; r++)
            for (int cc = 0; cc < 4; cc++)
                acc[r][cc] = __builtin_amdgcn_mfma_f32_16x16x32_bf16(
                    a[r], b[cc], acc[r][cc], 0, 0, 0);
        __syncthreads();
    }

    // weight per 64-row strip: its 128-row block index is 2R + (wr>>1)
    int rblk = 2 * R + (wr >> 1);
    float weight = (c > rblk) ? 2.0f : ((c == rblk) ? 1.0f : 0.0f);

    // Epilogue: C/D layout col = lane&15, row = (lane>>4)*4 + e  [m89-verified]
    int rb0 = R * 16 + wr * 4;
    int cb0 = c * 8 + wc * 4;
    int rquad = (lane >> 4) * 4;
    int lcol  = lane & 15;
    float sqc[4], scv[4];
    int tc[4];
    for (int cc = 0; cc < 4; cc++) {
        int col = (cb0 + cc) * 16 + lcol;
        sqc[cc] = sq[col]; scv[cc] = s[col]; tc[cc] = tgt[col];
    }

    float partial = 0.0f;
    const float deps2 = (float)D_DIM * EPS * EPS;
    for (int r = 0; r < 4; r++) {
        int rowbase = (rb0 + r) * 16 + rquad;
        for (int e = 0; e < 4; e++) {
            int row = rowbase + e;
            float sqr = sq[row];
            float sr  = s[row];
            int tr = tgt[row];
            for (int cc = 0; cc < 4; cc++) {
                float g  = acc[r][cc][e];
                float d2 = sqr + sqc[cc] - 2.0f * g
                         + 2.0f * EPS * (sr - scv[cc]) + deps2;
                partial += (tr == tc[cc]) ? d2 : fmaxf(MARGIN - d2, 0.0f);
            }
        }
    }

    partial *= weight;
    for (int off = 32; off > 0; off >>= 1)
        partial += __shfl_down(partial, off, 64);
    if (lane == 0) wsum[wave] = partial;
    __syncthreads();
    if (threadIdx.x == 0) {
        float v = 0.f;
        for (int i = 0; i < 8; i++) v += wsum[i];
        partials[p] = v;
    }
}

// Final reduce: NTILE partials -> out[0] with 1/N scale.
__global__ __launch_bounds__(256)
void reduce_kernel(const float* __restrict__ partials, float* __restrict__ out) {
    __shared__ float wsum[4];
    int t = threadIdx.x;
    float v = 0.0f;
    for (int i = t; i < NTILE; i += 256) v += partials[i];
    for (int off = 32; off > 0; off >>= 1)
        v += __shfl_down(v, off, 64);
    int wave = t >> 6, lane = t & 63;
    if (lane == 0) wsum[wave] = v;
    __syncthreads();
    if (t == 0)
        out[0] = (wsum[0] + wsum[1] + wsum[2] + wsum[3]) * (1.0f / (float)N_ROWS);
}

extern "C" void kernel_launch(void* const* d_in, const int* in_sizes, int n_in,
                              void* d_out, int out_size, void* d_ws, size_t ws_size,
                              hipStream_t stream) {
    const float* X  = (const float*)d_in[0];
    const int* tgt  = (const int*)d_in[1];   // harness passes integer inputs as int32
    float* out      = (float*)d_out;

    unsigned short* Xs = (unsigned short*)d_ws;                       // 4 MB bf16 swizzled
    float* sq = (float*)((char*)d_ws + (size_t)N_ROWS * D_DIM * 2);   // 32 KB
    float* s  = sq + N_ROWS;                                          // 32 KB
    float* partials = s + N_ROWS;                                     // ~4.2 KB

    prep_kernel<<<N_ROWS / 16, 256, 0, stream>>>(X, Xs, sq, s);
    gram_loss_kernel<<<NTILE, 512, 0, stream>>>(Xs, sq, s, tgt, partials);
    reduce_kernel<<<1, 256, 0, stream>>>(partials, out);
}

// Round 6
// 89.908 us; speedup vs baseline: 1.1289x; 1.1289x over previous
//
#include <hip/hip_runtime.h>

#define N_ROWS 8192
#define D_DIM  256
#define EPS    1e-6f
#define MARGIN 0.5f
#define NBLK   64                    // 8192 / 128 tiles per dim
#define NTRI   (NBLK * (NBLK + 1) / 2)   // 2080 upper-triangle blocks

typedef __bf16 bf16x8 __attribute__((ext_vector_type(8)));
typedef float  f32x4  __attribute__((ext_vector_type(4)));

// round-to-nearest-even fp32 -> bf16
__device__ inline unsigned short f2bf(float f) {
    unsigned u = __float_as_uint(f);
    return (unsigned short)((u + 0x7FFFu + ((u >> 16) & 1u)) >> 16);
}

// async global->LDS, 16B/lane; LDS dst = wave-uniform base + lane*16 (m104/m108)
__device__ inline void gl_lds16(const void* g, void* l) {
    __builtin_amdgcn_global_load_lds(
        (const __attribute__((address_space(1))) unsigned int*)g,
        (__attribute__((address_space(3))) unsigned int*)l, 16, 0, 0);
}

// Prep v2 (kept from R5 — layout verified end-to-end by R5's absmax=0 pass):
// chunk (rb,kb) = 1KB = rows [rb*16,+16) x k [kb*32,+32), elem (row,k) at
// lane=((k>>3)&3)*16+(row&15), j=k&7. One wave writes whole chunks:
// store = base + lane*16, perfectly coalesced (R4 v1's scatter stores ~10us).
// Reads: per row, the two float4s cover 128 contiguous bytes -> L2 merges.
__global__ __launch_bounds__(256)
void prep_kernel(const float* __restrict__ X,
                 unsigned short* __restrict__ Xs,
                 float* __restrict__ sq, float* __restrict__ s) {
    __shared__ float lsq[64], ls[64];
    int t = threadIdx.x;
    int w = t >> 6, l = t & 63;
    int rb = blockIdx.x;
    int row = rb * 16 + (l & 15);
    int q   = l >> 4;                      // k-quarter 0..3
    float psq = 0.f, ps = 0.f;
    for (int h = 0; h < 2; h++) {
        int kb = 2 * w + h;
        int k0 = kb * 32 + q * 8;
        const float* xp = X + (size_t)row * D_DIM + k0;
        float4 v0 = ((const float4*)xp)[0];
        float4 v1 = ((const float4*)xp)[1];
        float xv[8] = {v0.x, v0.y, v0.z, v0.w, v1.x, v1.y, v1.z, v1.w};
        for (int i = 0; i < 8; i++) { psq += xv[i] * xv[i]; ps += xv[i]; }
        unsigned w0 = (unsigned)f2bf(xv[0]) | ((unsigned)f2bf(xv[1]) << 16);
        unsigned w1 = (unsigned)f2bf(xv[2]) | ((unsigned)f2bf(xv[3]) << 16);
        unsigned w2 = (unsigned)f2bf(xv[4]) | ((unsigned)f2bf(xv[5]) << 16);
        unsigned w3 = (unsigned)f2bf(xv[6]) | ((unsigned)f2bf(xv[7]) << 16);
        *(uint4*)(Xs + (size_t)(rb * 8 + kb) * 512 + (size_t)l * 8) =
            make_uint4(w0, w1, w2, w3);
    }
    // reduce k-quarters: lanes with same (l&15) share a row
    psq += __shfl_xor(psq, 16, 64); psq += __shfl_xor(psq, 32, 64);
    ps  += __shfl_xor(ps,  16, 64); ps  += __shfl_xor(ps,  32, 64);
    if (l < 16) { lsq[w * 16 + l] = psq; ls[w * 16 + l] = ps; }
    __syncthreads();
    if (t < 16) {
        float aq = 0.f, as = 0.f;
        for (int i = 0; i < 4; i++) { aq += lsq[i * 16 + t]; as += ls[i * 16 + t]; }
        sq[rb * 16 + t] = aq; s[rb * 16 + t] = as;
    }
}

// Gram + loss: EXACT R4 structure (87.9us baseline). 128x128 block tile,
// 256 threads = 4 waves (2x2), triangular 1D grid, double-buffered LDS via
// global_load_lds. Off-diagonal blocks weighted 2x (symmetry).
__global__ __launch_bounds__(256)
void gram_loss_kernel(const unsigned short* __restrict__ Xs,
                      const float* __restrict__ sq, const float* __restrict__ s,
                      const int* __restrict__ tgt,
                      float* __restrict__ partials) {
    __shared__ __align__(16) unsigned short ldsA[2][4096];  // 8KB per buffer
    __shared__ __align__(16) unsigned short ldsB[2][4096];
    __shared__ float wsum[4];

    // decode linear block id -> (bi, bj), bj >= bi.  f(i) = i*64 - i*(i-1)/2
    int p = blockIdx.x;
    int bi = (int)(64.5f - sqrtf(64.5f * 64.5f - 2.0f * (float)p));
    if (bi < 0) bi = 0; if (bi > 63) bi = 63;
    while ((bi + 1) * 64 - ((bi + 1) * bi) / 2 <= p) bi++;
    while (bi * 64 - (bi * (bi - 1)) / 2 > p) bi--;
    int bj = bi + (p - (bi * 64 - (bi * (bi - 1)) / 2));
    float weight = (bi == bj) ? 1.0f : 2.0f;

    int wave = threadIdx.x >> 6;
    int lane = threadIdx.x & 63;
    int wr = wave >> 1, wc = wave & 1;

    const char* xb = (const char*)Xs;
    const char* sA0 = xb + ((size_t)(bi * 8 + 2 * wave)     * 8) * 1024 + (size_t)lane * 16;
    const char* sA1 = xb + ((size_t)(bi * 8 + 2 * wave + 1) * 8) * 1024 + (size_t)lane * 16;
    const char* sB0 = xb + ((size_t)(bj * 8 + 2 * wave)     * 8) * 1024 + (size_t)lane * 16;
    const char* sB1 = xb + ((size_t)(bj * 8 + 2 * wave + 1) * 8) * 1024 + (size_t)lane * 16;
    unsigned short* dA0 = &ldsA[0][(2 * wave)     * 512];
    unsigned short* dA1 = &ldsA[0][(2 * wave + 1) * 512];
    unsigned short* dB0 = &ldsB[0][(2 * wave)     * 512];
    unsigned short* dB1 = &ldsB[0][(2 * wave + 1) * 512];

    f32x4 acc[4][4];
    for (int r = 0; r < 4; r++)
        for (int c = 0; c < 4; c++)
            for (int e = 0; e < 4; e++) acc[r][c][e] = 0.0f;

    gl_lds16(sA0, dA0); gl_lds16(sA1, dA1);
    gl_lds16(sB0, dB0); gl_lds16(sB1, dB1);
    __syncthreads();

    const unsigned short* fA = &ldsA[0][(wr * 4) * 512] + lane * 8;
    const unsigned short* fB = &ldsB[0][(wc * 4) * 512] + lane * 8;

    for (int kb = 0; kb < 8; kb++) {
        int cur = kb & 1, nxt = cur ^ 1;
        if (kb < 7) {
            size_t ko = (size_t)(kb + 1) * 1024;
            size_t bo = (size_t)nxt * 8192;
            gl_lds16(sA0 + ko, (char*)dA0 + bo);
            gl_lds16(sA1 + ko, (char*)dA1 + bo);
            gl_lds16(sB0 + ko, (char*)dB0 + bo);
            gl_lds16(sB1 + ko, (char*)dB1 + bo);
        }
        const unsigned short* a_p = fA + (size_t)cur * 4096;
        const unsigned short* b_p = fB + (size_t)cur * 4096;
        bf16x8 a[4], b[4];
        for (int r = 0; r < 4; r++) a[r] = *(const bf16x8*)(a_p + r * 512);
        for (int c = 0; c < 4; c++) b[c] = *(const bf16x8*)(b_p + c * 512);
        for (int r = 0; r < 4; r++)
            for (int c = 0; c < 4; c++)
                acc[r][c] = __builtin_amdgcn_mfma_f32_16x16x32_bf16(
                    a[r], b[c], acc[r][c], 0, 0, 0);
        __syncthreads();
    }

    // Epilogue: C/D layout col = lane&15, row = (lane>>4)*4 + e  [m89-verified]
    int rb0 = bi * 8 + wr * 4;
    int cb0 = bj * 8 + wc * 4;
    int rquad = (lane >> 4) * 4;
    int lcol  = lane & 15;
    float sqc[4], scv[4];
    int tc[4];
    for (int c = 0; c < 4; c++) {
        int col = (cb0 + c) * 16 + lcol;
        sqc[c] = sq[col]; scv[c] = s[col]; tc[c] = tgt[col];
    }

    float partial = 0.0f;
    const float deps2 = (float)D_DIM * EPS * EPS;
    for (int r = 0; r < 4; r++) {
        int rowbase = (rb0 + r) * 16 + rquad;
        for (int e = 0; e < 4; e++) {
            int row = rowbase + e;
            float sqr = sq[row];
            float sr  = s[row];
            int tr = tgt[row];
            for (int c = 0; c < 4; c++) {
                float g  = acc[r][c][e];
                float d2 = sqr + sqc[c] - 2.0f * g
                         + 2.0f * EPS * (sr - scv[c]) + deps2;
                partial += (tr == tc[c]) ? d2 : fmaxf(MARGIN - d2, 0.0f);
            }
        }
    }

    partial *= weight;
    for (int off = 32; off > 0; off >>= 1)
        partial += __shfl_down(partial, off, 64);
    if (lane == 0) wsum[wave] = partial;
    __syncthreads();
    if (threadIdx.x == 0)
        partials[p] = wsum[0] + wsum[1] + wsum[2] + wsum[3];
}

// Final reduce: NTRI partials -> out[0] with 1/N scale.
__global__ __launch_bounds__(256)
void reduce_kernel(const float* __restrict__ partials, float* __restrict__ out) {
    __shared__ float wsum[4];
    int t = threadIdx.x;
    float v = 0.0f;
    for (int i = t; i < NTRI; i += 256) v += partials[i];
    for (int off = 32; off > 0; off >>= 1)
        v += __shfl_down(v, off, 64);
    int wave = t >> 6, lane = t & 63;
    if (lane == 0) wsum[wave] = v;
    __syncthreads();
    if (t == 0)
        out[0] = (wsum[0] + wsum[1] + wsum[2] + wsum[3]) * (1.0f / (float)N_ROWS);
}

extern "C" void kernel_launch(void* const* d_in, const int* in_sizes, int n_in,
                              void* d_out, int out_size, void* d_ws, size_t ws_size,
                              hipStream_t stream) {
    const float* X  = (const float*)d_in[0];
    const int* tgt  = (const int*)d_in[1];   // harness passes integer inputs as int32
    float* out      = (float*)d_out;

    unsigned short* Xs = (unsigned short*)d_ws;                       // 4 MB bf16 swizzled
    float* sq = (float*)((char*)d_ws + (size_t)N_ROWS * D_DIM * 2);   // 32 KB
    float* s  = sq + N_ROWS;                                          // 32 KB
    float* partials = s + N_ROWS;                                     // ~8 KB

    prep_kernel<<<N_ROWS / 16, 256, 0, stream>>>(X, Xs, sq, s);
    gram_loss_kernel<<<NTRI, 256, 0, stream>>>(Xs, sq, s, tgt, partials);
    reduce_kernel<<<1, 256, 0, stream>>>(partials, out);
}